// Round 10
// baseline (172.957 us; speedup 1.0000x reference)
//
#include <hip/hip_runtime.h>
#include <math.h>

#define NCOLS 5000
#define NF4   1250            // NCOLS / 4
#define HALF_F4 625           // f4 elements per half-row
#define BLOCK_A 640           // covers 625 f4 slots in ONE load round
#define NWAVES_A 10
#define TOPKK 10
#define CAP 512               // candidate capacity per half (expect ~50-150)
#define WS_STRIDE 48          // words per half-row record in d_ws
#define BLOCK_B 256

// Monotone-ascending mapping float -> uint32 (total order on finite floats).
__device__ __forceinline__ unsigned mono_f32(float f) {
  unsigned u = __float_as_uint(f);
  return (u & 0x80000000u) ? ~u : (u | 0x80000000u);
}

__device__ __forceinline__ float wave_sum_f(float v) {
#pragma unroll
  for (int o = 1; o < 64; o <<= 1) v += __shfl_xor(v, o);
  return v;
}
__device__ __forceinline__ int wave_sum_i(int v) {
#pragma unroll
  for (int o = 1; o < 64; o <<= 1) v += __shfl_xor(v, o);
  return v;
}
__device__ __forceinline__ unsigned wave_max_u(unsigned v) {
#pragma unroll
  for (int o = 1; o < 64; o <<= 1) {
    unsigned w = __shfl_xor(v, o);
    v = w > v ? w : v;
  }
  return v;
}

// ---------------------------------------------------------------------------
// Kernel A: one block per HALF-row. Single load round (4 vec loads), partial
// scalar sums + exact per-half top/bottom-10 (key,value) lists -> d_ws.
// ws layout per half (48 words):
//   [0] nv (uint bits)  [1] sq  [2] sp  [3] seyy  [4] seyu  [5] aspu  [6] aspd
//   [8..17]  top keys (uint bits)   [18..27] top u-values
//   [28..37] bottom keys (~mono)    [38..47] bottom d-values
// ---------------------------------------------------------------------------
extern "C" __global__ __launch_bounds__(BLOCK_A)
void partial_kernel(const float* __restrict__ up, const float* __restrict__ down,
                    const float* __restrict__ yt, const int* __restrict__ masks,
                    float* __restrict__ ws) {
  __shared__ float red_f[6][NWAVES_A];
  __shared__ int red_i[NWAVES_A];
  __shared__ unsigned t1w_t[NWAVES_A], t1w_b[NWAVES_A];
  __shared__ unsigned skeys_t[CAP];
  __shared__ float    svals_t[CAP];
  __shared__ unsigned skeys_b[CAP];
  __shared__ float    svals_b[CAP];
  __shared__ int ct, cb;

  const int tid = threadIdx.x;
  const int lane = tid & 63;
  const int wv = tid >> 6;
  const int half = blockIdx.x & 1;
  const int row = blockIdx.x >> 1;
  const long long b4 = (long long)row * NF4 + half * HALF_F4;

  if (tid == 0) { ct = 0; cb = 0; }

  // ---- ONE load round: 4 unconditional clamped vector loads.
  const bool inb = tid < HALF_F4;
  const int fo = inb ? tid : HALF_F4 - 1;
  const float4 y4 = ((const float4*)yt)[b4 + fo];
  const float4 u4 = ((const float4*)up)[b4 + fo];
  const float4 d4 = ((const float4*)down)[b4 + fo];
  const int4   m4 = ((const int4*)masks)[b4 + fo];

  // ---- 4 elements of math. Invalid -> fill -1000 so exp->0 kills terms.
  unsigned km[4];
  float uv[4], dv[4];
  int nv_l = 0;
  float sq = 0.f, sp = 0.f, seyy = 0.f, seyu = 0.f;
  float pu = 1.f, pd = 1.f;            // softplus product trick (4 factors)
  unsigned tmax = 0u, tbmax = 0u;
  const float* yp = (const float*)&y4;
  const float* upp = (const float*)&u4;
  const float* dp = (const float*)&d4;
  const int* mp = (const int*)&m4;
#pragma unroll
  for (int c = 0; c < 4; ++c) {
    const bool valid = inb && (mp[c] > 0);
    const float y = valid ? yp[c] : -1000.f;
    const float u = valid ? upp[c] : -1000.f;
    const float d = valid ? dp[c] : -1000.f;
    const unsigned kd = valid ? mono_f32(y) : 0u;
    km[c] = kd;
    uv[c] = u;
    dv[c] = d;
    const unsigned kb = valid ? ~kd : 0u;
    tmax = kd > tmax ? kd : tmax;
    tbmax = kb > tbmax ? kb : tbmax;
    nv_l += valid ? 1 : 0;
    const float ey = __expf(y);        // 0 for invalid
    const float eu = __expf(u);
    const float ed = __expf(d);
    sq += ey;
    seyy += ey * y;
    seyu += ey * u;
    sp += eu;
    pu *= 1.f + eu;                    // <= (1+e^6)^4 ~ 2.7e10, fp32-safe
    pd *= 1.f + ed;
  }
  float aspu = __logf(pu);             // sum softplus(u) this thread
  float aspd = __logf(pd);

  // ---- Wave reduces.
  nv_l = wave_sum_i(nv_l);
  sq = wave_sum_f(sq);
  sp = wave_sum_f(sp);
  seyy = wave_sum_f(seyy);
  seyu = wave_sum_f(seyu);
  aspu = wave_sum_f(aspu);
  aspd = wave_sum_f(aspd);
  if (lane == 0) {
    red_i[wv] = nv_l;
    red_f[0][wv] = sq;  red_f[1][wv] = sp;
    red_f[2][wv] = seyy; red_f[3][wv] = seyu;
    red_f[4][wv] = aspu; red_f[5][wv] = aspd;
  }

  // ---- Per-wave filter: 10 pops over per-thread top-1 maxes => >=10
  //      distinct elements >= t1w; block max t1 keeps top-10 superset.
  {
    unsigned v = tmax, t1 = 0u;
#pragma unroll 1
    for (int r = 0; r < TOPKK; ++r) {
      unsigned m = wave_max_u(v);
      if (v == m) v = 0u;
      t1 = m;
    }
    if (lane == 0) t1w_t[wv] = t1;
  }
  {
    unsigned v = tbmax, t1 = 0u;
#pragma unroll 1
    for (int r = 0; r < TOPKK; ++r) {
      unsigned m = wave_max_u(v);
      if (v == m) v = 0u;
      t1 = m;
    }
    if (lane == 0) t1w_b[wv] = t1;
  }
  __syncthreads();

  unsigned t1 = 0u, t1b = 0u;
#pragma unroll
  for (int w = 0; w < NWAVES_A; ++w) {
    t1 = t1w_t[w] > t1 ? t1w_t[w] : t1;
    t1b = t1w_b[w] > t1b ? t1w_b[w] : t1b;
  }

  // ---- Compact candidates (key, value) into LDS.
#pragma unroll
  for (int c = 0; c < 4; ++c) {
    const unsigned kd = km[c];
    if (kd != 0u) {
      if (kd >= t1) {
        int i = atomicAdd(&ct, 1);
        if (i < CAP) { skeys_t[i] = kd; svals_t[i] = uv[c]; }
      }
      const unsigned kb = ~kd;
      if (kb >= t1b) {
        int i = atomicAdd(&cb, 1);
        if (i < CAP) { skeys_b[i] = kb; svals_b[i] = dv[c]; }
      }
    }
  }
  __syncthreads();

  float* wsh = ws + (size_t)blockIdx.x * WS_STRIDE;

  if (tid == 0) {
    int nv = 0;
    float SQ = 0.f, SP = 0.f, SYY = 0.f, SYU = 0.f, ASU = 0.f, ASD = 0.f;
#pragma unroll
    for (int w = 0; w < NWAVES_A; ++w) {
      nv += red_i[w];
      SQ += red_f[0][w]; SP += red_f[1][w];
      SYY += red_f[2][w]; SYU += red_f[3][w];
      ASU += red_f[4][w]; ASD += red_f[5][w];
    }
    wsh[0] = __uint_as_float((unsigned)nv);
    wsh[1] = SQ; wsh[2] = SP; wsh[3] = SYY; wsh[4] = SYU;
    wsh[5] = ASU; wsh[6] = ASD; wsh[7] = 0.f;
  }

  // ---- Wave 0: pop exact top-10 (key,val) to ws. Wave 1: bottom-10.
  if (wv == 0) {
    const int n = ct < CAP ? ct : CAP;
    unsigned kk[8];
#pragma unroll
    for (int i = 0; i < 8; ++i) {
      const int idx = i * 64 + lane;
      kk[i] = (idx < n) ? skeys_t[idx] : 0u;
    }
#pragma unroll 1
    for (int r = 0; r < TOPKK; ++r) {
      unsigned lm = 0u;
#pragma unroll
      for (int i = 0; i < 8; ++i) lm = kk[i] > lm ? kk[i] : lm;
      const unsigned m = wave_max_u(lm);
      float vm = 0.f;
      bool done = false;
#pragma unroll
      for (int i = 0; i < 8; ++i) {
        if (!done && m != 0u && kk[i] == m) {
          vm = svals_t[i * 64 + lane];
          kk[i] = 0u;
          done = true;
        }
      }
      vm = wave_sum_f(vm);             // exactly one lane contributes
      if (lane == 0) {
        wsh[8 + r] = __uint_as_float(m);
        wsh[18 + r] = vm;
      }
    }
  } else if (wv == 1) {
    const int n = cb < CAP ? cb : CAP;
    unsigned kk[8];
#pragma unroll
    for (int i = 0; i < 8; ++i) {
      const int idx = i * 64 + lane;
      kk[i] = (idx < n) ? skeys_b[idx] : 0u;
    }
#pragma unroll 1
    for (int r = 0; r < TOPKK; ++r) {
      unsigned lm = 0u;
#pragma unroll
      for (int i = 0; i < 8; ++i) lm = kk[i] > lm ? kk[i] : lm;
      const unsigned m = wave_max_u(lm);
      float vm = 0.f;
      bool done = false;
#pragma unroll
      for (int i = 0; i < 8; ++i) {
        if (!done && m != 0u && kk[i] == m) {
          vm = svals_b[i * 64 + lane];
          kk[i] = 0u;
          done = true;
        }
      }
      vm = wave_sum_f(vm);
      if (lane == 0) {
        wsh[28 + r] = __uint_as_float(m);
        wsh[38 + r] = vm;
      }
    }
  }
}

// ---------------------------------------------------------------------------
// Kernel B: one thread per row. Merge the two halves: scalars add; top lists
// merge by k pop rounds over 20 (key,val) pairs (static indexing only).
// ---------------------------------------------------------------------------
extern "C" __global__ __launch_bounds__(BLOCK_B)
void finalize_kernel(const float* __restrict__ ws, float* __restrict__ out,
                     float inv_nrows, int nrows) {
  const int row = blockIdx.x * BLOCK_B + threadIdx.x;
  float loss = 0.f;
  if (row < nrows) {
    const float* h0 = ws + (size_t)(2 * row) * WS_STRIDE;
    const float* h1 = h0 + WS_STRIDE;
    const int nv = (int)__float_as_uint(h0[0]) + (int)__float_as_uint(h1[0]);
    if (nv > 0) {
      const float SQ = h0[1] + h1[1];
      const float SP = h0[2] + h1[2];
      const float SYY = h0[3] + h1[3];
      const float SYU = h0[4] + h1[4];
      const float ASU = h0[5] + h1[5];
      const float ASD = h0[6] + h1[6];
      const int k = nv < TOPKK ? nv : TOPKK;

      unsigned tk[20]; float tv[20];
      unsigned bk[20]; float bv[20];
#pragma unroll
      for (int i = 0; i < TOPKK; ++i) {
        tk[i] = __float_as_uint(h0[8 + i]);  tv[i] = h0[18 + i];
        tk[10 + i] = __float_as_uint(h1[8 + i]); tv[10 + i] = h1[18 + i];
        bk[i] = __float_as_uint(h0[28 + i]); bv[i] = h0[38 + i];
        bk[10 + i] = __float_as_uint(h1[28 + i]); bv[10 + i] = h1[38 + i];
      }

      float SU = 0.f, SD = 0.f;
#pragma unroll
      for (int r = 0; r < TOPKK; ++r) {
        if (r < k) {
          unsigned bm = 0u;
#pragma unroll
          for (int i = 0; i < 20; ++i) bm = tk[i] > bm ? tk[i] : bm;
          bool done = false;
#pragma unroll
          for (int i = 0; i < 20; ++i) {
            if (!done && bm != 0u && tk[i] == bm) { SU += tv[i]; tk[i] = 0u; done = true; }
          }
          unsigned bm2 = 0u;
#pragma unroll
          for (int i = 0; i < 20; ++i) bm2 = bk[i] > bm2 ? bk[i] : bm2;
          bool done2 = false;
#pragma unroll
          for (int i = 0; i < 20; ++i) {
            if (!done2 && bm2 != 0u && bk[i] == bm2) { SD += bv[i]; bk[i] = 0u; done2 = true; }
          }
        }
      }

      // KL closed form: (Seyy - Seyu)/Sq - log(Sq) + log(Sp)
      const float kl = (SYY - SYU) / SQ - __logf(SQ) + __logf(SP);
      const float up_loss = ASU - SU;
      const float dn_loss = ASD - SD;
      loss = (up_loss + 0.5f * dn_loss + 0.3f * kl) / (float)nv;
    }
  }
  loss = wave_sum_f(loss * inv_nrows);
  if ((threadIdx.x & 63) == 0) atomicAdd(out, loss);
}

extern "C" void kernel_launch(void* const* d_in, const int* in_sizes, int n_in,
                              void* d_out, int out_size, void* d_ws, size_t ws_size,
                              hipStream_t stream) {
  const float* up_logits   = (const float*)d_in[0];
  const float* down_logits = (const float*)d_in[1];
  const float* y_true      = (const float*)d_in[2];
  const int*   masks       = (const int*)d_in[3];

  const int nrows = in_sizes[0] / NCOLS;

  hipMemsetAsync(d_out, 0, sizeof(float) * (size_t)out_size, stream);
  partial_kernel<<<nrows * 2, BLOCK_A, 0, stream>>>(up_logits, down_logits,
                                                    y_true, masks, (float*)d_ws);
  finalize_kernel<<<(nrows + BLOCK_B - 1) / BLOCK_B, BLOCK_B, 0, stream>>>(
      (const float*)d_ws, (float*)d_out, 1.0f / (float)nrows, nrows);
}

// Round 11
// 165.134 us; speedup vs baseline: 1.0474x; 1.0474x over previous
//
#include <hip/hip_runtime.h>
#include <math.h>

#define NCOLS 5000
#define NF4   1250            // NCOLS / 4
#define HALF_F4 625           // f4 elements per half-row
#define BLOCK_A 640           // covers 625 f4 slots in ONE load round
#define NWAVES_A 10
#define TOPKK 10
#define CAP 512               // candidate capacity per half (expect ~50-150)
#define WS_STRIDE 48          // words per half-row record in d_ws
#define BLOCK_B 256           // 4 waves -> 4 rows per block

// Monotone-ascending mapping float -> uint32 (total order on finite floats).
__device__ __forceinline__ unsigned mono_f32(float f) {
  unsigned u = __float_as_uint(f);
  return (u & 0x80000000u) ? ~u : (u | 0x80000000u);
}

__device__ __forceinline__ float wave_sum_f(float v) {
#pragma unroll
  for (int o = 1; o < 64; o <<= 1) v += __shfl_xor(v, o);
  return v;
}
__device__ __forceinline__ int wave_sum_i(int v) {
#pragma unroll
  for (int o = 1; o < 64; o <<= 1) v += __shfl_xor(v, o);
  return v;
}
__device__ __forceinline__ unsigned wave_max_u(unsigned v) {
#pragma unroll
  for (int o = 1; o < 64; o <<= 1) {
    unsigned w = __shfl_xor(v, o);
    v = w > v ? w : v;
  }
  return v;
}

// ---------------------------------------------------------------------------
// Kernel A: one block per HALF-row. Single load round (4 vec loads), partial
// scalar sums + exact per-half top/bottom-10 (key,value) lists -> d_ws.
// ws layout per half (48 words):
//   [0] nv (uint bits)  [1] sq  [2] sp  [3] seyy  [4] seyu  [5] aspu  [6] aspd
//   [8..17]  top keys (uint bits)   [18..27] top u-values
//   [28..37] bottom keys (~mono)    [38..47] bottom d-values
// ---------------------------------------------------------------------------
extern "C" __global__ __launch_bounds__(BLOCK_A)
void partial_kernel(const float* __restrict__ up, const float* __restrict__ down,
                    const float* __restrict__ yt, const int* __restrict__ masks,
                    float* __restrict__ ws) {
  __shared__ float red_f[6][NWAVES_A];
  __shared__ int red_i[NWAVES_A];
  __shared__ unsigned t1w_t[NWAVES_A], t1w_b[NWAVES_A];
  __shared__ unsigned skeys_t[CAP];
  __shared__ float    svals_t[CAP];
  __shared__ unsigned skeys_b[CAP];
  __shared__ float    svals_b[CAP];
  __shared__ int ct, cb;

  const int tid = threadIdx.x;
  const int lane = tid & 63;
  const int wv = tid >> 6;
  const int half = blockIdx.x & 1;
  const int row = blockIdx.x >> 1;
  const long long b4 = (long long)row * NF4 + half * HALF_F4;

  if (tid == 0) { ct = 0; cb = 0; }

  // ---- ONE load round: 4 unconditional clamped vector loads.
  const bool inb = tid < HALF_F4;
  const int fo = inb ? tid : HALF_F4 - 1;
  const float4 y4 = ((const float4*)yt)[b4 + fo];
  const float4 u4 = ((const float4*)up)[b4 + fo];
  const float4 d4 = ((const float4*)down)[b4 + fo];
  const int4   m4 = ((const int4*)masks)[b4 + fo];

  // ---- 4 elements of math. Invalid -> fill -1000 so exp->0 kills terms.
  unsigned km[4];
  float uv[4], dv[4];
  int nv_l = 0;
  float sq = 0.f, sp = 0.f, seyy = 0.f, seyu = 0.f;
  float pu = 1.f, pd = 1.f;            // softplus product trick (4 factors)
  unsigned tmax = 0u, tbmax = 0u;
  const float* yp = (const float*)&y4;
  const float* upp = (const float*)&u4;
  const float* dp = (const float*)&d4;
  const int* mp = (const int*)&m4;
#pragma unroll
  for (int c = 0; c < 4; ++c) {
    const bool valid = inb && (mp[c] > 0);
    const float y = valid ? yp[c] : -1000.f;
    const float u = valid ? upp[c] : -1000.f;
    const float d = valid ? dp[c] : -1000.f;
    const unsigned kd = valid ? mono_f32(y) : 0u;
    km[c] = kd;
    uv[c] = u;
    dv[c] = d;
    const unsigned kb = valid ? ~kd : 0u;
    tmax = kd > tmax ? kd : tmax;
    tbmax = kb > tbmax ? kb : tbmax;
    nv_l += valid ? 1 : 0;
    const float ey = __expf(y);        // 0 for invalid
    const float eu = __expf(u);
    const float ed = __expf(d);
    sq += ey;
    seyy += ey * y;
    seyu += ey * u;
    sp += eu;
    pu *= 1.f + eu;                    // <= (1+e^6)^4 ~ 2.7e10, fp32-safe
    pd *= 1.f + ed;
  }
  float aspu = __logf(pu);             // sum softplus(u) this thread
  float aspd = __logf(pd);

  // ---- Wave reduces.
  nv_l = wave_sum_i(nv_l);
  sq = wave_sum_f(sq);
  sp = wave_sum_f(sp);
  seyy = wave_sum_f(seyy);
  seyu = wave_sum_f(seyu);
  aspu = wave_sum_f(aspu);
  aspd = wave_sum_f(aspd);
  if (lane == 0) {
    red_i[wv] = nv_l;
    red_f[0][wv] = sq;  red_f[1][wv] = sp;
    red_f[2][wv] = seyy; red_f[3][wv] = seyu;
    red_f[4][wv] = aspu; red_f[5][wv] = aspd;
  }

  // ---- Per-wave filter: 10 pops over per-thread top-1 maxes => >=10
  //      distinct elements >= t1w; block max t1 keeps top-10 superset.
  {
    unsigned v = tmax, t1 = 0u;
#pragma unroll 1
    for (int r = 0; r < TOPKK; ++r) {
      unsigned m = wave_max_u(v);
      if (v == m) v = 0u;
      t1 = m;
    }
    if (lane == 0) t1w_t[wv] = t1;
  }
  {
    unsigned v = tbmax, t1 = 0u;
#pragma unroll 1
    for (int r = 0; r < TOPKK; ++r) {
      unsigned m = wave_max_u(v);
      if (v == m) v = 0u;
      t1 = m;
    }
    if (lane == 0) t1w_b[wv] = t1;
  }
  __syncthreads();

  unsigned t1 = 0u, t1b = 0u;
#pragma unroll
  for (int w = 0; w < NWAVES_A; ++w) {
    t1 = t1w_t[w] > t1 ? t1w_t[w] : t1;
    t1b = t1w_b[w] > t1b ? t1w_b[w] : t1b;
  }

  // ---- Compact candidates (key, value) into LDS.
#pragma unroll
  for (int c = 0; c < 4; ++c) {
    const unsigned kd = km[c];
    if (kd != 0u) {
      if (kd >= t1) {
        int i = atomicAdd(&ct, 1);
        if (i < CAP) { skeys_t[i] = kd; svals_t[i] = uv[c]; }
      }
      const unsigned kb = ~kd;
      if (kb >= t1b) {
        int i = atomicAdd(&cb, 1);
        if (i < CAP) { skeys_b[i] = kb; svals_b[i] = dv[c]; }
      }
    }
  }
  __syncthreads();

  float* wsh = ws + (size_t)blockIdx.x * WS_STRIDE;

  if (tid == 0) {
    int nv = 0;
    float SQ = 0.f, SP = 0.f, SYY = 0.f, SYU = 0.f, ASU = 0.f, ASD = 0.f;
#pragma unroll
    for (int w = 0; w < NWAVES_A; ++w) {
      nv += red_i[w];
      SQ += red_f[0][w]; SP += red_f[1][w];
      SYY += red_f[2][w]; SYU += red_f[3][w];
      ASU += red_f[4][w]; ASD += red_f[5][w];
    }
    wsh[0] = __uint_as_float((unsigned)nv);
    wsh[1] = SQ; wsh[2] = SP; wsh[3] = SYY; wsh[4] = SYU;
    wsh[5] = ASU; wsh[6] = ASD; wsh[7] = 0.f;
  }

  // ---- Wave 0: pop exact top-10 (key,val) to ws. Wave 1: bottom-10.
  if (wv == 0) {
    const int n = ct < CAP ? ct : CAP;
    unsigned kk[8];
#pragma unroll
    for (int i = 0; i < 8; ++i) {
      const int idx = i * 64 + lane;
      kk[i] = (idx < n) ? skeys_t[idx] : 0u;
    }
#pragma unroll 1
    for (int r = 0; r < TOPKK; ++r) {
      unsigned lm = 0u;
#pragma unroll
      for (int i = 0; i < 8; ++i) lm = kk[i] > lm ? kk[i] : lm;
      const unsigned m = wave_max_u(lm);
      float vm = 0.f;
      bool done = false;
#pragma unroll
      for (int i = 0; i < 8; ++i) {
        if (!done && m != 0u && kk[i] == m) {
          vm = svals_t[i * 64 + lane];
          kk[i] = 0u;
          done = true;
        }
      }
      vm = wave_sum_f(vm);             // exactly one lane contributes
      if (lane == 0) {
        wsh[8 + r] = __uint_as_float(m);
        wsh[18 + r] = vm;
      }
    }
  } else if (wv == 1) {
    const int n = cb < CAP ? cb : CAP;
    unsigned kk[8];
#pragma unroll
    for (int i = 0; i < 8; ++i) {
      const int idx = i * 64 + lane;
      kk[i] = (idx < n) ? skeys_b[idx] : 0u;
    }
#pragma unroll 1
    for (int r = 0; r < TOPKK; ++r) {
      unsigned lm = 0u;
#pragma unroll
      for (int i = 0; i < 8; ++i) lm = kk[i] > lm ? kk[i] : lm;
      const unsigned m = wave_max_u(lm);
      float vm = 0.f;
      bool done = false;
#pragma unroll
      for (int i = 0; i < 8; ++i) {
        if (!done && m != 0u && kk[i] == m) {
          vm = svals_b[i * 64 + lane];
          kk[i] = 0u;
          done = true;
        }
      }
      vm = wave_sum_f(vm);
      if (lane == 0) {
        wsh[28 + r] = __uint_as_float(m);
        wsh[38 + r] = vm;
      }
    }
  }
}

// ---------------------------------------------------------------------------
// Kernel B: ONE WAVE PER ROW (256 blocks x 4 waves). Lanes 0-19 hold the 20
// (key,val) pairs of the two halves; lanes 32-46 load the 14 scalars;
// __shfl broadcasts. Merge = k pop rounds of wave_max over register keys.
// ---------------------------------------------------------------------------
extern "C" __global__ __launch_bounds__(BLOCK_B)
void finalize_kernel(const float* __restrict__ ws, float* __restrict__ out,
                     float inv_nrows, int nrows) {
  __shared__ float part[BLOCK_B / 64];
  const int tid = threadIdx.x;
  const int lane = tid & 63;
  const int wv = tid >> 6;
  const int row = blockIdx.x * (BLOCK_B / 64) + wv;

  float loss = 0.f;
  if (row < nrows) {
    const float* h = ws + (size_t)(2 * row) * WS_STRIDE;

    float ld = 0.f;
    unsigned key_t = 0u, key_b = 0u;
    float val_t = 0.f, val_b = 0.f;
    if (lane < 20) {
      const int hh = lane >= 10 ? 1 : 0;
      const int i = lane - 10 * hh;
      const float* hb = h + hh * WS_STRIDE;
      key_t = __float_as_uint(hb[8 + i]);
      val_t = hb[18 + i];
      key_b = __float_as_uint(hb[28 + i]);
      val_b = hb[38 + i];
    } else if (lane >= 32 && lane < 39) {
      ld = h[lane - 32];                 // h0 scalars [0..6]
    } else if (lane >= 40 && lane < 47) {
      ld = h[WS_STRIDE + (lane - 40)];   // h1 scalars [0..6]
    }

    const int nv = (int)__float_as_uint(__shfl(ld, 32)) +
                   (int)__float_as_uint(__shfl(ld, 40));
    if (nv > 0) {
      const float SQ  = __shfl(ld, 33) + __shfl(ld, 41);
      const float SP  = __shfl(ld, 34) + __shfl(ld, 42);
      const float SYY = __shfl(ld, 35) + __shfl(ld, 43);
      const float SYU = __shfl(ld, 36) + __shfl(ld, 44);
      const float ASU = __shfl(ld, 37) + __shfl(ld, 45);
      const float ASD = __shfl(ld, 38) + __shfl(ld, 46);
      const int k = nv < TOPKK ? nv : TOPKK;

      // Merge: pop k rounds over the 20 keys (lanes >=20 hold 0).
      unsigned kt = key_t;
      float su = 0.f;
#pragma unroll 1
      for (int r = 0; r < k; ++r) {
        const unsigned m = wave_max_u(kt);
        if (m != 0u && kt == m) { su += val_t; kt = 0u; }
      }
      unsigned kb = key_b;
      float sd = 0.f;
#pragma unroll 1
      for (int r = 0; r < k; ++r) {
        const unsigned m = wave_max_u(kb);
        if (m != 0u && kb == m) { sd += val_b; kb = 0u; }
      }
      su = wave_sum_f(su);
      sd = wave_sum_f(sd);

      // KL closed form: (Seyy - Seyu)/Sq - log(Sq) + log(Sp)
      const float kl = (SYY - SYU) / SQ - __logf(SQ) + __logf(SP);
      const float up_loss = ASU - su;
      const float dn_loss = ASD - sd;
      loss = (up_loss + 0.5f * dn_loss + 0.3f * kl) / (float)nv;
    }
  }

  if (lane == 0) part[wv] = loss * inv_nrows;
  __syncthreads();
  if (tid == 0) {
    float s = 0.f;
#pragma unroll
    for (int w = 0; w < BLOCK_B / 64; ++w) s += part[w];
    atomicAdd(out, s);
  }
}

extern "C" void kernel_launch(void* const* d_in, const int* in_sizes, int n_in,
                              void* d_out, int out_size, void* d_ws, size_t ws_size,
                              hipStream_t stream) {
  const float* up_logits   = (const float*)d_in[0];
  const float* down_logits = (const float*)d_in[1];
  const float* y_true      = (const float*)d_in[2];
  const int*   masks       = (const int*)d_in[3];

  const int nrows = in_sizes[0] / NCOLS;

  hipMemsetAsync(d_out, 0, sizeof(float) * (size_t)out_size, stream);
  partial_kernel<<<nrows * 2, BLOCK_A, 0, stream>>>(up_logits, down_logits,
                                                    y_true, masks, (float*)d_ws);
  const int rows_per_block = BLOCK_B / 64;
  finalize_kernel<<<(nrows + rows_per_block - 1) / rows_per_block, BLOCK_B, 0,
                    stream>>>((const float*)d_ws, (float*)d_out,
                              1.0f / (float)nrows, nrows);
}